// Round 16
// baseline (176.188 us; speedup 1.0000x reference)
//
#include <hip/hip_runtime.h>
#include <hip/hip_bf16.h>

#define BATCH 8192
#define IDIM 256
#define ODIM 256

#define NC 8
#define IPC 32            // i-values per K-chunk
#define THREADS 256
#define RG_TOT 4096       // (2*IDIM*KGRID)/8

typedef __attribute__((ext_vector_type(8))) short short8;
typedef __attribute__((ext_vector_type(4))) float float4v;
typedef __attribute__((ext_vector_type(16))) float float16v;
typedef __attribute__((ext_vector_type(4))) unsigned int uint4v;

#define INV2PI 0.15915494309189535f

// pack two f32 -> (bf16(c) | bf16(s)<<16), RTNE (prep_w only)
__device__ __forceinline__ unsigned int bf16pack(float c, float s) {
    union { float f; unsigned int u; } a, b;
    a.f = c; b.f = s;
    unsigned int ua = a.u + (0x7fffu + ((a.u >> 16) & 1u));
    unsigned int ub = b.u + (0x7fffu + ((b.u >> 16) & 1u));
    return (ua >> 16) | (ub & 0xffff0000u);
}

// single-instruction pack: lo = bf16(c), hi = bf16(s)
__device__ __forceinline__ unsigned int cvtpk(float c, float s) {
    unsigned int r;
    asm("v_cvt_pk_bf16_f32 %0, %1, %2" : "=v"(r) : "v"(c), "v"(s));
    return r;
}

__device__ __forceinline__ float16v mfma(short8 a, uint4v b, float16v c) {
    return __builtin_amdgcn_mfma_f32_32x32x16_bf16(
        a, __builtin_bit_cast(short8, b), c, 0, 0, 0);
}

// W[2][256][256][64] f32 -> Bw2 k-step slab layout (verified R12/R14/R15):
// [chunk][wn][s=256][g=2][jl=128] 16B-slots; one (chunk,wn) region = 1MB,
// one k-step slab = 4KB contiguous.
__global__ void prep_w(const float4v* __restrict__ W, uint4v* __restrict__ Bw2) {
    int tid = blockIdx.x * 256 + threadIdx.x;   // 1,048,576 threads
    int rg = tid & 4095;
    int j = tid >> 12;
    float4v c4 = W[j * 4096 + rg];
    float4v s4 = W[1048576 + j * 4096 + rg];
    uint4v o;
    o.x = bf16pack(c4.x, s4.x);
    o.y = bf16pack(c4.y, s4.y);
    o.z = bf16pack(c4.z, s4.z);
    o.w = bf16pack(c4.w, s4.w);
    int chunk = rg >> 9, rl = rg & 511, s = rl >> 1, g = rl & 1;
    int wn = j >> 7, jl = j & 127;
    Bw2[((((size_t)(chunk * 2 + wn) * 256 + s) * 2 + g) << 7) + jl] = o;
}

// 4 waves/block, wave tile 32 rows x 128 cols (acc = 64 AGPR -> ~132 unified
// regs -> 3 waves/SIMD, the occupancy the 64x128 tile could not reach).
// B staged through a 3-slot LDS ring (48KB) of half-i slab groups via
// global_load_lds, staged 2 phases ahead, counted vmcnt(4), 2 raw barriers
// per phase. 1 rowset/wave keeps trig+pack per MFMA equal to R14 (R13's
// VALU trap avoided); B from LDS (R10's L1 trap avoided).
__global__ __launch_bounds__(THREADS, 3) void kan_main(
    const float* __restrict__ x,
    const char* __restrict__ Bw2,
    float* __restrict__ part)
{
    __shared__ __align__(16) uint4v ring[3][4][256];   // 48 KB

    const int bx = blockIdx.x;
    const int chunk = bx & 7;          // K-chunk == XCD id (1024 blocks)
    const int wn = (bx >> 3) & 1;      // 128-col half
    const int mb = bx >> 4;            // M-block 0..63 (128 rows)
    const int b0 = mb * 128;
    const int i0 = chunk * IPC;
    const int t = threadIdx.x;
    const int lane = t & 63;
    const int wave = t >> 6;           // 0..3 -> 32-row slice
    const int g = lane >> 5;           // k-octet half
    const int l31 = lane & 31;

    const int row = b0 + wave * 32 + l31;
    const float* xr = x + (size_t)row * IDIM + i0;

    // ---- B staging pointers (verified R14) ----
    const char* gq = Bw2 + ((size_t)(chunk * 2 + wn) << 20)
                   + wave * 1024 + (size_t)lane * 16;
    char* lds0 = (char*)&ring[0][0][0] + wave * 1024;

    // prologue: stage phases 0,1 (slots 0,1) -> 8 loads outstanding
    #pragma unroll
    for (int ii = 0; ii < 2; ++ii)
        #pragma unroll
        for (int u = 0; u < 4; ++u)
            __builtin_amdgcn_global_load_lds(
                (const __attribute__((address_space(1))) void*)(gq + ii * 16384 + u * 4096),
                (__attribute__((address_space(3))) void*)(lds0 + ii * 16384 + u * 4096),
                16, 0, 0);
    gq += 32768;

    float16v acc[4];
    #pragma unroll
    for (int f = 0; f < 4; ++f) acc[f] = (float16v)(0.0f);

    const float mbase = (float)(4 * g + 1);

    float xv = xr[0];
    float xnext = xr[1];
    int rs = 0;                        // ring read slot

    for (int p = 0; p < IPC; ++p) {
        float c0[4], s0[4], c8, s8;

        // ---------- phase 0 (k-steps 0..3 of i=p) ----------
        asm volatile("s_waitcnt vmcnt(4)" ::: "memory");
        asm volatile("s_barrier" ::: "memory");
        {
            const float xk = xv * INV2PI;
            #pragma unroll
            for (int u = 0; u < 4; ++u) {
                float r = __builtin_amdgcn_fractf(xk * (mbase + (float)u));
                c0[u] = __builtin_amdgcn_cosf(r);
                s0[u] = __builtin_amdgcn_sinf(r);
            }
            float tt = __builtin_amdgcn_fractf(8.0f * xk);
            c8 = __builtin_amdgcn_cosf(tt);
            s8 = __builtin_amdgcn_sinf(tt);
        }
        #pragma unroll
        for (int q = 0; q < 4; ++q) {
            uint4v w;
            #pragma unroll
            for (int u = 0; u < 4; ++u) w[u] = cvtpk(c0[u], s0[u]);
            // advance +8 multipliers (also bridges into phase 1)
            #pragma unroll
            for (int u = 0; u < 4; ++u) {
                float cn = fmaf(-s0[u], s8, c0[u] * c8);
                float sn = fmaf( c0[u], s8, s0[u] * c8);
                c0[u] = cn; s0[u] = sn;
            }
            const uint4v* sk = &ring[rs][q][g * 128 + l31];
            uint4v bf0 = sk[0], bf1 = sk[32], bf2 = sk[64], bf3 = sk[96];
            short8 a = __builtin_bit_cast(short8, w);
            __builtin_amdgcn_s_setprio(1);
            acc[0] = mfma(a, bf0, acc[0]);
            acc[1] = mfma(a, bf1, acc[1]);
            acc[2] = mfma(a, bf2, acc[2]);
            acc[3] = mfma(a, bf3, acc[3]);
            __builtin_amdgcn_s_setprio(0);
        }
        asm volatile("s_barrier" ::: "memory");
        {   // stage phase +2 into slot (rs+2)%3
            const int ss = (rs >= 1) ? rs - 1 : 2;
            #pragma unroll
            for (int u = 0; u < 4; ++u)
                __builtin_amdgcn_global_load_lds(
                    (const __attribute__((address_space(1))) void*)(gq + u * 4096),
                    (__attribute__((address_space(3))) void*)(lds0 + ss * 16384 + u * 4096),
                    16, 0, 0);
            gq += 16384;
        }
        rs = (rs < 2) ? rs + 1 : 0;

        // ---------- phase 1 (k-steps 4..7 of i=p) ----------
        asm volatile("s_waitcnt vmcnt(4)" ::: "memory");
        asm volatile("s_barrier" ::: "memory");
        #pragma unroll
        for (int q = 0; q < 4; ++q) {
            uint4v w;
            #pragma unroll
            for (int u = 0; u < 4; ++u) w[u] = cvtpk(c0[u], s0[u]);
            if (q < 3) {
                #pragma unroll
                for (int u = 0; u < 4; ++u) {
                    float cn = fmaf(-s0[u], s8, c0[u] * c8);
                    float sn = fmaf( c0[u], s8, s0[u] * c8);
                    c0[u] = cn; s0[u] = sn;
                }
            }
            const uint4v* sk = &ring[rs][q][g * 128 + l31];
            uint4v bf0 = sk[0], bf1 = sk[32], bf2 = sk[64], bf3 = sk[96];
            short8 a = __builtin_bit_cast(short8, w);
            __builtin_amdgcn_s_setprio(1);
            acc[0] = mfma(a, bf0, acc[0]);
            acc[1] = mfma(a, bf1, acc[1]);
            acc[2] = mfma(a, bf2, acc[2]);
            acc[3] = mfma(a, bf3, acc[3]);
            __builtin_amdgcn_s_setprio(0);
        }
        asm volatile("s_barrier" ::: "memory");
        {
            const int ss = (rs >= 1) ? rs - 1 : 2;
            #pragma unroll
            for (int u = 0; u < 4; ++u)
                __builtin_amdgcn_global_load_lds(
                    (const __attribute__((address_space(1))) void*)(gq + u * 4096),
                    (__attribute__((address_space(3))) void*)(lds0 + ss * 16384 + u * 4096),
                    16, 0, 0);
            gq += 16384;
        }
        rs = (rs < 2) ? rs + 1 : 0;

        // rotate x: xnext was loaded a full i ago (latency covered)
        xv = xnext;
        xnext = xr[(p + 2 < IPC) ? (p + 2) : (IPC - 1)];
    }

    // drain in-flight LDS-writing loads before exit (next block reuses LDS)
    asm volatile("s_waitcnt vmcnt(0)" ::: "memory");

    // ---- store partials: part[chunk][b][j] ----
    // 32x32 C/D (verified R4..R15): col = lane&31,
    // row = (v&3) + 8*(v>>2) + 4*(lane>>5)
    const int cb = wn * 128 + l31;
    const int rb = b0 + wave * 32 + 4 * g;
    float* pc = part + (size_t)chunk * (BATCH * ODIM);
    #pragma unroll
    for (int f = 0; f < 4; ++f)
        #pragma unroll
        for (int v = 0; v < 16; ++v) {
            int r = rb + (v & 3) + 8 * (v >> 2);
            pc[(size_t)r * ODIM + cb + f * 32] = acc[f][v];
        }
}

__global__ void reduce_bias(const float4v* __restrict__ part,
                            const float4v* __restrict__ bias,
                            float4v* __restrict__ out)
{
    const int tid = blockIdx.x * 256 + threadIdx.x;   // 524288 float4s
    const int Q = BATCH * ODIM / 4;
    float4v r = part[tid];
    #pragma unroll
    for (int c = 1; c < NC; ++c) r += part[tid + c * Q];
    r += bias[tid & 63];
    out[tid] = r;
}

extern "C" void kernel_launch(void* const* d_in, const int* in_sizes, int n_in,
                              void* d_out, int out_size, void* d_ws, size_t ws_size,
                              hipStream_t stream)
{
    const float* x = (const float*)d_in[0];
    const float* W = (const float*)d_in[1];
    const float* bias = (const float*)d_in[2];
    float* out = (float*)d_out;

    const size_t bw_bytes = (size_t)RG_TOT * 256 * 16;   // 16.78 MB

    char* Bw2 = (char*)d_ws;
    float* part = (float*)((char*)d_ws + bw_bytes);      // 67.1 MB (ws>=84MB proven R3)

    prep_w<<<4096, 256, 0, stream>>>((const float4v*)W, (uint4v*)Bw2);
    // 1024 blocks x 256 thr; LDS 48KB -> 3 blocks/CU; ~132 regs -> 3 waves/SIMD
    kan_main<<<(BATCH / 128) * 2 * NC, THREADS, 0, stream>>>(x, Bw2, part);
    reduce_bias<<<(BATCH * ODIM / 4) / 256, 256, 0, stream>>>(
        (const float4v*)part, (const float4v*)bias, (float4v*)out);
}

// Round 17
// 156.250 us; speedup vs baseline: 1.1276x; 1.1276x over previous
//
#include <hip/hip_runtime.h>
#include <hip/hip_bf16.h>

#define BATCH 8192
#define IDIM 256
#define ODIM 256

#define NC 8
#define IPC 32            // i-values per K-chunk
#define THREADS 256
#define RG_TOT 4096       // (2*IDIM*KGRID)/8

typedef __attribute__((ext_vector_type(8))) short short8;
typedef __attribute__((ext_vector_type(4))) float float4v;
typedef __attribute__((ext_vector_type(16))) float float16v;
typedef __attribute__((ext_vector_type(4))) unsigned int uint4v;

#define INV2PI 0.15915494309189535f

// pack two f32 -> (bf16(c) | bf16(s)<<16), RTNE (prep_w only)
__device__ __forceinline__ unsigned int bf16pack(float c, float s) {
    union { float f; unsigned int u; } a, b;
    a.f = c; b.f = s;
    unsigned int ua = a.u + (0x7fffu + ((a.u >> 16) & 1u));
    unsigned int ub = b.u + (0x7fffu + ((b.u >> 16) & 1u));
    return (ua >> 16) | (ub & 0xffff0000u);
}

// single-instruction pack: lo = bf16(c), hi = bf16(s)
__device__ __forceinline__ unsigned int cvtpk(float c, float s) {
    unsigned int r;
    asm("v_cvt_pk_bf16_f32 %0, %1, %2" : "=v"(r) : "v"(c), "v"(s));
    return r;
}

__device__ __forceinline__ float16v mfma(short8 a, uint4v b, float16v c) {
    return __builtin_amdgcn_mfma_f32_32x32x16_bf16(
        a, __builtin_bit_cast(short8, b), c, 0, 0, 0);
}

// W[2][256][256][64] f32 -> Bw2 k-step slab layout (verified R12/R14/R15):
// [chunk][wn][s=256][g=2][jl=128] 16B-slots; one (chunk,wn) region = 1MB,
// one k-step slab = 4KB contiguous, one half-i = 4 slabs = 16KB.
__global__ void prep_w(const float4v* __restrict__ W, uint4v* __restrict__ Bw2) {
    int tid = blockIdx.x * 256 + threadIdx.x;   // 1,048,576 threads
    int rg = tid & 4095;
    int j = tid >> 12;
    float4v c4 = W[j * 4096 + rg];
    float4v s4 = W[1048576 + j * 4096 + rg];
    uint4v o;
    o.x = bf16pack(c4.x, s4.x);
    o.y = bf16pack(c4.y, s4.y);
    o.z = bf16pack(c4.z, s4.z);
    o.w = bf16pack(c4.w, s4.w);
    int chunk = rg >> 9, rl = rg & 511, s = rl >> 1, g = rl & 1;
    int wn = j >> 7, jl = j & 127;
    Bw2[((((size_t)(chunk * 2 + wn) * 256 + s) * 2 + g) << 7) + jl] = o;
}

// 4 waves/block, wave tile 64 rows x 128 cols (verified R11/R14 layouts).
// B staged through a DEPTH-4 ring of half-i slab groups (4 x 16KB = 64KB)
// with ONE raw barrier per phase: a wave at barrier(n) has MFMA-consumed
// its phase-(n-1) reads, so slot (n+3)%4 == (n-1)%4 is reclaimable without
// a consume-done barrier. Stage issued right after the barrier (early-issue),
// counted vmcnt(8) keeps 2 phases of loads in flight. 64 barriers/block
// (R14's consume-barriers eliminated), half the jitter window per barrier.
__global__ __launch_bounds__(THREADS, 2) void kan_main(
    const float* __restrict__ x,
    const char* __restrict__ Bw2,
    float* __restrict__ part)
{
    __shared__ __align__(16) uint4v ring[4][4][256];   // 64 KB

    const int bx = blockIdx.x;
    const int chunk = bx & 7;          // K-chunk == XCD id (512 blocks)
    const int wn = (bx >> 3) & 1;      // 128-col half
    const int mb = bx >> 4;            // M-block 0..31 (256 rows)
    const int b0 = mb * 256;
    const int i0 = chunk * IPC;
    const int t = threadIdx.x;
    const int lane = t & 63;
    const int wave = t >> 6;           // 0..3 -> 64-row slice
    const int g = lane >> 5;           // k-octet half
    const int l31 = lane & 31;

    const int row0 = b0 + wave * 64 + l31;
    const float* xr0 = x + (size_t)row0 * IDIM + i0;
    const float* xr1 = xr0 + (size_t)32 * IDIM;   // rowset 1 (+32 rows)

    // ---- B staging pointers (verified R14) ----
    const char* gq = Bw2 + ((size_t)(chunk * 2 + wn) << 20)
                   + wave * 1024 + (size_t)lane * 16;
    char* lds0 = (char*)&ring[0][0][0] + wave * 1024;

    // prologue: stage phases 0,1,2 (slots 0,1,2) -> 12 loads outstanding
    #pragma unroll
    for (int ii = 0; ii < 3; ++ii)
        #pragma unroll
        for (int u = 0; u < 4; ++u)
            __builtin_amdgcn_global_load_lds(
                (const __attribute__((address_space(1))) void*)(gq + ii * 16384 + u * 4096),
                (__attribute__((address_space(3))) void*)(lds0 + ii * 16384 + u * 4096),
                16, 0, 0);
    gq += 3 * 16384;

    float16v acc[2][4];
    #pragma unroll
    for (int rr = 0; rr < 2; ++rr)
        #pragma unroll
        for (int f = 0; f < 4; ++f) acc[rr][f] = (float16v)(0.0f);

    const float mbase = (float)(4 * g + 1);

    // trig init for i = 0
    float cI0[4], sI0[4], cI1[4], sI1[4], c80n, s80n, c81n, s81n;
    {
        const float xk0 = xr0[0] * INV2PI, xk1 = xr1[0] * INV2PI;
        #pragma unroll
        for (int u = 0; u < 4; ++u) {
            float r = __builtin_amdgcn_fractf(xk0 * (mbase + (float)u));
            cI0[u] = __builtin_amdgcn_cosf(r); sI0[u] = __builtin_amdgcn_sinf(r);
            r = __builtin_amdgcn_fractf(xk1 * (mbase + (float)u));
            cI1[u] = __builtin_amdgcn_cosf(r); sI1[u] = __builtin_amdgcn_sinf(r);
        }
        float tt = __builtin_amdgcn_fractf(8.0f * xk0);
        c80n = __builtin_amdgcn_cosf(tt); s80n = __builtin_amdgcn_sinf(tt);
        tt = __builtin_amdgcn_fractf(8.0f * xk1);
        c81n = __builtin_amdgcn_cosf(tt); s81n = __builtin_amdgcn_sinf(tt);
    }
    float xn0 = xr0[1], xn1 = xr1[1];

    for (int p = 0; p < IPC; ++p) {
        // running trig state for this i
        float c0[4], s0[4], c1[4], s1[4];
        #pragma unroll
        for (int u = 0; u < 4; ++u) {
            c0[u] = cI0[u]; s0[u] = sI0[u];
            c1[u] = cI1[u]; s1[u] = sI1[u];
        }
        const float c80 = c80n, s80 = s80n, c81 = c81n, s81 = s81n;

        #define PACK(W0, W1) do {                                   \
            _Pragma("unroll") for (int u_ = 0; u_ < 4; ++u_) {      \
                W0[u_] = cvtpk(c0[u_], s0[u_]);                     \
                W1[u_] = cvtpk(c1[u_], s1[u_]);                     \
            } } while (0)
        #define ROT() do {                                          \
            _Pragma("unroll") for (int u_ = 0; u_ < 4; ++u_) {      \
                float cn_ = fmaf(-s0[u_], s80, c0[u_] * c80);       \
                float sn_ = fmaf( c0[u_], s80, s0[u_] * c80);       \
                c0[u_] = cn_; s0[u_] = sn_;                         \
                cn_ = fmaf(-s1[u_], s81, c1[u_] * c81);             \
                sn_ = fmaf( c1[u_], s81, s1[u_] * c81);             \
                c1[u_] = cn_; s1[u_] = sn_;                         \
            } } while (0)
        #define BURST(SB, Q) do {                                   \
            const uint4v* sk_ = (SB) + (Q) * 256;                   \
            uint4v bf0_ = sk_[0];                                   \
            uint4v bf1_ = sk_[32];                                  \
            uint4v bf2_ = sk_[64];                                  \
            uint4v bf3_ = sk_[96];                                  \
            uint4v w0_, w1_;                                        \
            PACK(w0_, w1_);                                         \
            short8 a0_ = __builtin_bit_cast(short8, w0_);           \
            short8 a1_ = __builtin_bit_cast(short8, w1_);           \
            __builtin_amdgcn_s_setprio(1);                          \
            acc[0][0] = mfma(a0_, bf0_, acc[0][0]);                 \
            acc[1][0] = mfma(a1_, bf0_, acc[1][0]);                 \
            acc[0][1] = mfma(a0_, bf1_, acc[0][1]);                 \
            acc[1][1] = mfma(a1_, bf1_, acc[1][1]);                 \
            acc[0][2] = mfma(a0_, bf2_, acc[0][2]);                 \
            acc[1][2] = mfma(a1_, bf2_, acc[1][2]);                 \
            acc[0][3] = mfma(a0_, bf3_, acc[0][3]);                 \
            acc[1][3] = mfma(a1_, bf3_, acc[1][3]);                 \
            __builtin_amdgcn_s_setprio(0);                          \
        } while (0)
        #define STAGE(SLOT) do {                                    \
            _Pragma("unroll") for (int u_ = 0; u_ < 4; ++u_)        \
                __builtin_amdgcn_global_load_lds(                   \
                    (const __attribute__((address_space(1))) void*)(gq + u_ * 4096), \
                    (__attribute__((address_space(3))) void*)(lds0 + (SLOT) * 16384 + u_ * 4096), \
                    16, 0, 0);                                      \
            gq += 16384;                                            \
        } while (0)

        // ---------- PHASE A: k-steps 0..3, slot (2p)&3 ----------
        {
            const int sA = (2 * p) & 3;
            asm volatile("s_waitcnt vmcnt(8)" ::: "memory");
            asm volatile("s_barrier" ::: "memory");
            STAGE((sA + 3) & 3);               // stage phase 2p+3
            const uint4v* sb = &ring[sA][0][g * 128 + l31];
            BURST(sb, 0); ROT();
            // next-i trig init drains under the MFMA bursts
            {
                const float xk0 = xn0 * INV2PI, xk1 = xn1 * INV2PI;
                #pragma unroll
                for (int u = 0; u < 4; ++u) {
                    float r = __builtin_amdgcn_fractf(xk0 * (mbase + (float)u));
                    cI0[u] = __builtin_amdgcn_cosf(r); sI0[u] = __builtin_amdgcn_sinf(r);
                    r = __builtin_amdgcn_fractf(xk1 * (mbase + (float)u));
                    cI1[u] = __builtin_amdgcn_cosf(r); sI1[u] = __builtin_amdgcn_sinf(r);
                }
                float tt = __builtin_amdgcn_fractf(8.0f * xk0);
                c80n = __builtin_amdgcn_cosf(tt); s80n = __builtin_amdgcn_sinf(tt);
                tt = __builtin_amdgcn_fractf(8.0f * xk1);
                c81n = __builtin_amdgcn_cosf(tt); s81n = __builtin_amdgcn_sinf(tt);
                const int p2 = (p + 2 < IPC) ? (p + 2) : (IPC - 1);
                xn0 = xr0[p2]; xn1 = xr1[p2];
            }
            BURST(sb, 1); ROT();
            BURST(sb, 2); ROT();
            BURST(sb, 3); ROT();
        }

        // ---------- PHASE B: k-steps 4..7, slot (2p+1)&3 ----------
        {
            const int sB = (2 * p + 1) & 3;
            asm volatile("s_waitcnt vmcnt(8)" ::: "memory");
            asm volatile("s_barrier" ::: "memory");
            STAGE((sB + 3) & 3);               // stage phase 2p+4
            const uint4v* sb = &ring[sB][0][g * 128 + l31];
            BURST(sb, 0); ROT();
            BURST(sb, 1); ROT();
            BURST(sb, 2); ROT();
            BURST(sb, 3);
        }

        #undef PACK
        #undef ROT
        #undef BURST
        #undef STAGE
    }

    // drain in-flight LDS-writing loads before exit (next block reuses LDS)
    asm volatile("s_waitcnt vmcnt(0)" ::: "memory");

    // ---- store partials: part[chunk][b][j] ----
    // 32x32 C/D (verified R4..R16): col = lane&31,
    // row = (v&3) + 8*(v>>2) + 4*(lane>>5)
    const int cb = wn * 128 + l31;
    float* pc = part + (size_t)chunk * (BATCH * ODIM);
    #pragma unroll
    for (int rt = 0; rt < 2; ++rt) {
        const int rb = b0 + wave * 64 + rt * 32 + 4 * g;
        #pragma unroll
        for (int f = 0; f < 4; ++f)
            #pragma unroll
            for (int v = 0; v < 16; ++v) {
                int r = rb + (v & 3) + 8 * (v >> 2);
                pc[(size_t)r * ODIM + cb + f * 32] = acc[rt][f][v];
            }
    }
}

__global__ void reduce_bias(const float4v* __restrict__ part,
                            const float4v* __restrict__ bias,
                            float4v* __restrict__ out)
{
    const int tid = blockIdx.x * 256 + threadIdx.x;   // 524288 float4s
    const int Q = BATCH * ODIM / 4;
    float4v r = part[tid];
    #pragma unroll
    for (int c = 1; c < NC; ++c) r += part[tid + c * Q];
    r += bias[tid & 63];
    out[tid] = r;
}

extern "C" void kernel_launch(void* const* d_in, const int* in_sizes, int n_in,
                              void* d_out, int out_size, void* d_ws, size_t ws_size,
                              hipStream_t stream)
{
    const float* x = (const float*)d_in[0];
    const float* W = (const float*)d_in[1];
    const float* bias = (const float*)d_in[2];
    float* out = (float*)d_out;

    const size_t bw_bytes = (size_t)RG_TOT * 256 * 16;   // 16.78 MB

    char* Bw2 = (char*)d_ws;
    float* part = (float*)((char*)d_ws + bw_bytes);      // 67.1 MB (ws>=84MB proven R3)

    prep_w<<<4096, 256, 0, stream>>>((const float4v*)W, (uint4v*)Bw2);
    // 512 blocks x 256 thr; LDS 64KB -> 2 blocks/CU; ~244 unified regs
    kan_main<<<(BATCH / 256) * 2 * NC, THREADS, 0, stream>>>(x, Bw2, part);
    reduce_bias<<<(BATCH * ODIM / 4) / 256, 256, 0, stream>>>(
        (const float4v*)part, (const float4v*)bias, (float4v*)out);
}